// Round 11
// baseline (487.447 us; speedup 1.0000x reference)
//
#include <hip/hip_runtime.h>
#include <hip/hip_bf16.h>
#include <stdint.h>

#define D_EMBED 1024
#define D_HID   4096
#define N_TOK   4096
#define N_EXP   8
#define CAP     4096
#define NROWA   8448

typedef __attribute__((ext_vector_type(4))) float f32x4;
typedef __attribute__((ext_vector_type(8))) short bf16x8;

__device__ __forceinline__ unsigned short f2bf(float f) {
    unsigned int u = __builtin_bit_cast(unsigned int, f);
    u += 0x7fffu + ((u >> 16) & 1u);
    return (unsigned short)(u >> 16);
}
__device__ __forceinline__ float bf2f(unsigned short h) {
    unsigned int u = ((unsigned int)h) << 16;
    return __builtin_bit_cast(float, u);
}
__device__ __forceinline__ void gload_lds16(const void* g, void* l) {
    __builtin_amdgcn_global_load_lds(
        (const __attribute__((address_space(1))) unsigned int*)g,
        (__attribute__((address_space(3))) unsigned int*)l, 16, 0, 0);
}

// ------- merged weight pack: blocks [0,32768) -> wt13, [32768,49152) -> wt2 -------
__global__ __launch_bounds__(256) void pack_all(const float* __restrict__ W1,
                                                const float* __restrict__ W3,
                                                const float* __restrict__ W2,
                                                unsigned short* __restrict__ wt13,
                                                unsigned short* __restrict__ wt2) {
    int b = blockIdx.x;
    if (b < 32768) {
        int idx = b * 256 + threadIdx.x;
        int pc = idx & 8191, s = (idx >> 13) & 127, e = idx >> 20;
        int g = pc >> 4;
        int rc = ((g >> 1) << 4) + (pc & 15);
        const float* src = (g & 1 ? W3 : W1) + (size_t)e * (D_EMBED * D_HID)
                         + (size_t)(s * 8) * D_HID + rc;
        bf16x8 o;
#pragma unroll
        for (int j = 0; j < 8; ++j) o[j] = (short)f2bf(src[(size_t)j * D_HID]);
        *reinterpret_cast<bf16x8*>(wt13 + (size_t)e * (D_EMBED * 2 * D_HID)
                                   + ((size_t)s * (2 * D_HID) + pc) * 8) = o;
    } else {
        int idx = (b - 32768) * 256 + threadIdx.x;
        int col = idx & 1023, s = (idx >> 10) & 511, e = idx >> 19;
        const float* src = W2 + (size_t)e * (D_HID * D_EMBED) + (size_t)(s * 8) * D_EMBED + col;
        bf16x8 o;
#pragma unroll
        for (int j = 0; j < 8; ++j) o[j] = (short)f2bf(src[(size_t)j * D_EMBED]);
        *reinterpret_cast<bf16x8*>(wt2 + (size_t)e * (D_HID * D_EMBED)
                                   + ((size_t)s * D_EMBED + col) * 8) = o;
    }
}

// ---------------- gating ----------------
__global__ __launch_bounds__(256) void gate_kernel(const float* __restrict__ x,
                                                   const float* __restrict__ Wg,
                                                   int* __restrict__ counts,
                                                   int* __restrict__ toks,
                                                   float* __restrict__ wgts,
                                                   int* __restrict__ slots) {
    int wave = threadIdx.x >> 6;
    int lane = threadIdx.x & 63;
    int tok = blockIdx.x * 4 + wave;
    const float* xp = x + (size_t)tok * D_EMBED;
    float acc[8] = {0, 0, 0, 0, 0, 0, 0, 0};
#pragma unroll
    for (int i = 0; i < 16; ++i) {
        int d = lane + 64 * i;
        float xv = xp[d];
        f32x4 w0 = *reinterpret_cast<const f32x4*>(Wg + (size_t)d * 8);
        f32x4 w1 = *reinterpret_cast<const f32x4*>(Wg + (size_t)d * 8 + 4);
        acc[0] += xv * w0[0]; acc[1] += xv * w0[1]; acc[2] += xv * w0[2]; acc[3] += xv * w0[3];
        acc[4] += xv * w1[0]; acc[5] += xv * w1[1]; acc[6] += xv * w1[2]; acc[7] += xv * w1[3];
    }
#pragma unroll
    for (int e = 0; e < 8; ++e)
        for (int s = 32; s; s >>= 1) acc[e] += __shfl_xor(acc[e], s, 64);
    if (lane == 0) {
        int i0 = 0; float v0 = acc[0];
#pragma unroll
        for (int e = 1; e < 8; ++e) if (acc[e] > v0) { v0 = acc[e]; i0 = e; }
        int i1 = -1; float v1 = -1e30f;
#pragma unroll
        for (int e = 0; e < 8; ++e) if (e != i0 && acc[e] > v1) { v1 = acc[e]; i1 = e; }
        float ex = __expf(v1 - v0);
        float w0 = 1.0f / (1.0f + ex);
        float w1 = 1.0f - w0;
        int p0 = atomicAdd(&counts[i0], 1);
        toks[i0 * CAP + p0] = tok; wgts[i0 * CAP + p0] = w0; slots[i0 * CAP + p0] = 0;
        int p1 = atomicAdd(&counts[i1], 1);
        toks[i1 * CAP + p1] = tok; wgts[i1 * CAP + p1] = w1; slots[i1 * CAP + p1] = 1;
    }
}

// ------- gather x rows into compacted k-packed A (build_map folded in) -------
__global__ __launch_bounds__(256) void gather_x_kernel(
    const float* __restrict__ x, const int* __restrict__ counts,
    const int* __restrict__ toks, const int* __restrict__ slots,
    int* __restrict__ tok2row, unsigned short* __restrict__ xg) {
    int rt = blockIdx.x;
    int e = -1, tb = 0, osum = 0, rowbase = 0, cnt = 0, off = 0;
    for (int ee = 0; ee < N_EXP; ++ee) {
        int c = counts[ee];
        int nt = (c + 63) >> 6;
        if (rt < tb + nt) { e = ee; rowbase = (rt - tb) << 6; cnt = c; off = osum; break; }
        tb += nt; osum += c;
    }
    if (e < 0) return;
    int kb = blockIdx.y;
    int t = threadIdx.x;
    if (kb == 0 && t < 64) {                    // build tok2row once per row chunk
        int pos = rowbase + t;
        if (pos < cnt) {
            int i = e * CAP + pos;
            tok2row[toks[i] * 2 + slots[i]] = off + pos;
        }
    }
    __shared__ unsigned short lds[64][72];
    int r = t >> 2, ck = t & 3;
    int pos = rowbase + r;
    unsigned short tmp[16];
    if (pos < cnt) {
        int tok = toks[e * CAP + pos];
        const float* src = x + (size_t)tok * D_EMBED + kb * 64 + ck * 16;
#pragma unroll
        for (int i = 0; i < 4; ++i) {
            f32x4 v = *reinterpret_cast<const f32x4*>(src + i * 4);
#pragma unroll
            for (int j = 0; j < 4; ++j) tmp[i * 4 + j] = f2bf(v[j]);
        }
    } else {
#pragma unroll
        for (int i = 0; i < 16; ++i) tmp[i] = 0;
    }
#pragma unroll
    for (int i = 0; i < 16; ++i) lds[r][ck * 16 + i] = tmp[i];
    __syncthreads();
    int sl = t >> 5, rr = (t & 31) * 2;
#pragma unroll
    for (int w = 0; w < 2; ++w) {
        int rw = rr + w;
        if (rowbase + rw >= cnt) continue;
        bf16x8 o;
#pragma unroll
        for (int j = 0; j < 8; ++j) o[j] = (short)lds[rw][sl * 8 + j];
        *reinterpret_cast<bf16x8*>(xg + ((size_t)(kb * 8 + sl) * NROWA + off + rowbase + rw) * 8) = o;
    }
}

// ======= GEMM1: 128x256p, ring-2 half-K(32), counted vmcnt(3), 3 blocks/CU =======
// grid (x = packed coltile 32, y = rowtile 72): XCD = x%8 -> B panel pinned per XCD
__global__ __launch_bounds__(512, 4) void gemm1_kernel(
    const unsigned short* __restrict__ xg,
    const unsigned short* __restrict__ wt13,
    const int* __restrict__ counts,
    const float* __restrict__ wgts,
    unsigned short* __restrict__ hp) {
    int rt = blockIdx.y;
    int e = -1, tb = 0, osum = 0, rowbase = 0, cnt = 0, off = 0;
#pragma unroll 1
    for (int ee = 0; ee < N_EXP; ++ee) {
        int c = counts[ee];
        int nt = (c + 127) >> 7;
        if (rt < tb + nt) { e = ee; rowbase = (rt - tb) << 7; cnt = c; off = osum; break; }
        tb += nt; osum += c;
    }
    if (e < 0) return;

    __shared__ __align__(16) char lds[2][24576];   // slot: A 8K | B 16K

    int t = threadIdx.x, lane = t & 63, w = t >> 6;   // 8 waves, 2Mx4N
    int wr = w >> 2, wc = w & 3;
    int q = lane >> 4, p = lane & 15;

    const size_t ASTEP = (size_t)4 * NROWA * 16;
    const size_t BSTEP = (size_t)4 * (2 * D_HID) * 16;
    const char* aS = (const char*)xg + ((size_t)(t >> 7) * NROWA + off + rowbase + (t & 127)) * 16;
    const char* bS0 = (const char*)wt13 + (size_t)e * D_EMBED * 2 * D_HID * 2
                    + ((size_t)(t >> 8) * (2 * D_HID) + blockIdx.x * 256 + (t & 255)) * 16;
    const char* bS1 = bS0 + (size_t)2 * (2 * D_HID) * 16;

    int wslot = 0;
    auto STG = [&]() {
        char* L = &lds[wslot][0];
        wslot ^= 1;
        gload_lds16(aS, L + t * 16);                 aS += ASTEP;
        gload_lds16(bS0, L + 8192 + t * 16);         bS0 += BSTEP;
        gload_lds16(bS1, L + 16384 + t * 16);        bS1 += BSTEP;
    };

    f32x4 acc[4][4] = {};

    STG();                                         // slot 0 <- data 0
#pragma unroll 1
    for (int h = 0; h < 32; ++h) {                 // K=1024, half-K=32
        if (h < 31) STG();                         // slot (h+1)&1 <- data h+1
        if (h < 31) asm volatile("s_waitcnt vmcnt(3)" ::: "memory");
        else        asm volatile("s_waitcnt vmcnt(0)" ::: "memory");
        __builtin_amdgcn_s_barrier();              // publish data h
        __builtin_amdgcn_sched_barrier(0);
        const char* L = &lds[h & 1][0];
        bf16x8 af[4], bf[4];
#pragma unroll
        for (int m = 0; m < 4; ++m)
            af[m] = *reinterpret_cast<const bf16x8*>(L + (q * 128 + wr * 64 + m * 16 + p) * 16);
#pragma unroll
        for (int n = 0; n < 4; ++n)
            bf[n] = *reinterpret_cast<const bf16x8*>(L + 8192 + (q * 256 + wc * 64 + n * 16 + p) * 16);
        __builtin_amdgcn_s_setprio(1);
#pragma unroll
        for (int n = 0; n < 4; ++n)
#pragma unroll
            for (int m = 0; m < 4; ++m)
                acc[m][n] = __builtin_amdgcn_mfma_f32_16x16x32_bf16(af[m], bf[n], acc[m][n], 0, 0, 0);
        __builtin_amdgcn_s_setprio(0);
    }

    // epilogue: (even n = W1, odd n = W3) -> SwiGLU * gate-weight -> hp (k-packed)
#pragma unroll
    for (int m = 0; m < 4; ++m) {
#pragma unroll
        for (int reg = 0; reg < 4; ++reg) {
            int rl = wr * 64 + m * 16 + q * 4 + reg;
            int grow = rowbase + rl;
            if (grow >= cnt) continue;
            float wgt = wgts[e * CAP + grow];
            size_t row = (size_t)(off + grow);
#pragma unroll
            for (int np = 0; np < 2; ++np) {
                float a1 = acc[m][2 * np][reg];
                float a3 = acc[m][2 * np + 1][reg];
                float hv = (a1 / (1.0f + __expf(-a1))) * a3 * wgt;
                int rc = (blockIdx.x * 8 + wc * 2 + np) * 16 + p;
                hp[((size_t)(rc >> 3) * NROWA + row) * 8 + (rc & 7)] = f2bf(hv);
            }
        }
    }
}

// ======= GEMM2: 128x256, split-K=2, ring-2 counted vmcnt, 3 blocks/CU =======
// grid (x = coltile 4, y = rowtile 72, z = split 2)
__global__ __launch_bounds__(512, 4) void gemm2_kernel(
    const unsigned short* __restrict__ hp,
    const unsigned short* __restrict__ wt2,
    const int* __restrict__ counts,
    unsigned short* __restrict__ pbuf) {
    int rt = blockIdx.y;
    int e = -1, tb = 0, osum = 0, rowbase = 0, cnt = 0, off = 0;
#pragma unroll 1
    for (int ee = 0; ee < N_EXP; ++ee) {
        int c = counts[ee];
        int nt = (c + 127) >> 7;
        if (rt < tb + nt) { e = ee; rowbase = (rt - tb) << 7; cnt = c; off = osum; break; }
        tb += nt; osum += c;
    }
    if (e < 0) return;
    int s2 = blockIdx.z;

    __shared__ __align__(16) char lds[2][24576];

    int t = threadIdx.x, lane = t & 63, w = t >> 6;
    int wr = w >> 2, wc = w & 3;
    int q = lane >> 4, p = lane & 15;

    const size_t ASTEP = (size_t)4 * NROWA * 16;
    const size_t BSTEP = (size_t)4 * D_EMBED * 16;
    const char* aS = (const char*)hp
        + ((size_t)(s2 * 256 + (t >> 7)) * NROWA + off + rowbase + (t & 127)) * 16;
    const char* bS0 = (const char*)wt2 + (size_t)e * D_HID * D_EMBED * 2
        + ((size_t)(s2 * 256 + (t >> 8)) * D_EMBED + blockIdx.x * 256 + (t & 255)) * 16;
    const char* bS1 = bS0 + (size_t)2 * D_EMBED * 16;

    int wslot = 0;
    auto STG = [&]() {
        char* L = &lds[wslot][0];
        wslot ^= 1;
        gload_lds16(aS, L + t * 16);                 aS += ASTEP;
        gload_lds16(bS0, L + 8192 + t * 16);         bS0 += BSTEP;
        gload_lds16(bS1, L + 16384 + t * 16);        bS1 += BSTEP;
    };

    f32x4 acc[4][4] = {};

    STG();
#pragma unroll 1
    for (int h = 0; h < 64; ++h) {                 // 2048 k per split, half-K=32
        if (h < 63) STG();
        if (h < 63) asm volatile("s_waitcnt vmcnt(3)" ::: "memory");
        else        asm volatile("s_waitcnt vmcnt(0)" ::: "memory");
        __builtin_amdgcn_s_barrier();
        __builtin_amdgcn_sched_barrier(0);
        const char* L = &lds[h & 1][0];
        bf16x8 af[4], bf[4];
#pragma unroll
        for (int m = 0; m < 4; ++m)
            af[m] = *reinterpret_cast<const bf16x8*>(L + (q * 128 + wr * 64 + m * 16 + p) * 16);
#pragma unroll
        for (int n = 0; n < 4; ++n)
            bf[n] = *reinterpret_cast<const bf16x8*>(L + 8192 + (q * 256 + wc * 64 + n * 16 + p) * 16);
        __builtin_amdgcn_s_setprio(1);
#pragma unroll
        for (int n = 0; n < 4; ++n)
#pragma unroll
            for (int m = 0; m < 4; ++m)
                acc[m][n] = __builtin_amdgcn_mfma_f32_16x16x32_bf16(af[m], bf[n], acc[m][n], 0, 0, 0);
        __builtin_amdgcn_s_setprio(0);
    }

    unsigned short* pb = pbuf + (size_t)s2 * 8192 * D_EMBED;
#pragma unroll
    for (int m = 0; m < 4; ++m)
#pragma unroll
        for (int reg = 0; reg < 4; ++reg) {
            int rl = wr * 64 + m * 16 + q * 4 + reg;
            int grow = rowbase + rl;
            if (grow >= cnt) continue;
            unsigned short* dst = pb + (size_t)(off + grow) * D_EMBED + blockIdx.x * 256 + wc * 64;
#pragma unroll
            for (int n = 0; n < 4; ++n) dst[n * 16 + p] = f2bf(acc[m][n][reg]);
        }
}

// ---------------- combine: out[tok] = sum over 2 rows x 2 k-splits (bf16 pbuf) ----------------
__global__ __launch_bounds__(256) void combine_kernel(const unsigned short* __restrict__ pbuf,
                                                      const int* __restrict__ tok2row,
                                                      float* __restrict__ out) {
    int i = blockIdx.x * 256 + threadIdx.x;        // N_TOK * 128, 8 cols each
    int tok = i >> 7, c0 = (i & 127) * 8;
    int r0 = tok2row[tok * 2], r1 = tok2row[tok * 2 + 1];
    const size_t SP = (size_t)8192 * D_EMBED;
    float s[8] = {0, 0, 0, 0, 0, 0, 0, 0};
#pragma unroll
    for (int sp = 0; sp < 2; ++sp) {
        bf16x8 a = *reinterpret_cast<const bf16x8*>(pbuf + sp * SP + (size_t)r0 * D_EMBED + c0);
        bf16x8 b = *reinterpret_cast<const bf16x8*>(pbuf + sp * SP + (size_t)r1 * D_EMBED + c0);
#pragma unroll
        for (int j = 0; j < 8; ++j)
            s[j] += bf2f((unsigned short)a[j]) + bf2f((unsigned short)b[j]);
    }
    float* op = out + (size_t)tok * D_EMBED + c0;
    f32x4 lo = {s[0], s[1], s[2], s[3]}, hi = {s[4], s[5], s[6], s[7]};
    *reinterpret_cast<f32x4*>(op) = lo;
    *reinterpret_cast<f32x4*>(op + 4) = hi;
}

extern "C" void kernel_launch(void* const* d_in, const int* in_sizes, int n_in,
                              void* d_out, int out_size, void* d_ws, size_t ws_size,
                              hipStream_t stream) {
    const float* x  = (const float*)d_in[0];
    const float* Wg = (const float*)d_in[1];
    const float* W1 = (const float*)d_in[2];
    const float* W3 = (const float*)d_in[3];
    const float* W2 = (const float*)d_in[4];
    float* out = (float*)d_out;

    char* ws = (char*)d_ws;
    size_t szW = (size_t)N_EXP * D_EMBED * D_HID;
    unsigned short* wt13 = (unsigned short*)ws; ws += szW * 2 * 2;     // 128 MB
    unsigned short* wt2  = (unsigned short*)ws; ws += szW * 2;         // 64 MB
    unsigned short* hp   = (unsigned short*)ws; ws += (size_t)(D_HID / 8) * NROWA * 8 * 2;
    unsigned short* xg   = (unsigned short*)ws; ws += (size_t)(D_EMBED / 8) * NROWA * 8 * 2;
    int*   toks    = (int*)ws;   ws += (size_t)N_EXP * CAP * 4;
    float* wgts    = (float*)ws; ws += (size_t)N_EXP * CAP * 4;
    int*   slots   = (int*)ws;   ws += (size_t)N_EXP * CAP * 4;
    int*   tok2row = (int*)ws;   ws += (size_t)N_TOK * 2 * 4;
    int*   counts  = (int*)ws;   ws += 8 * 4;
    // pbuf bf16 (32 MB: 2 splits x 8192 x 1024) aliases wt13 (dead after gemm1)
    unsigned short* pbuf = (unsigned short*)wt13;

    hipMemsetAsync(counts, 0, 8 * sizeof(int), stream);

    pack_all<<<49152, 256, 0, stream>>>(W1, W3, W2, wt13, wt2);
    gate_kernel<<<N_TOK / 4, 256, 0, stream>>>(x, Wg, counts, toks, wgts, slots);
    gather_x_kernel<<<dim3(136, D_EMBED / 64), 256, 0, stream>>>(x, counts, toks, slots, tok2row, xg);
    gemm1_kernel<<<dim3(32, 72), 512, 0, stream>>>(xg, wt13, counts, wgts, hp);
    gemm2_kernel<<<dim3(4, 72, 2), 512, 0, stream>>>(hp, wt2, counts, pbuf);
    combine_kernel<<<(N_TOK * 128) / 256, 256, 0, stream>>>(pbuf, tok2row, out);
}

// Round 12
// 472.943 us; speedup vs baseline: 1.0307x; 1.0307x over previous
//
#include <hip/hip_runtime.h>
#include <hip/hip_bf16.h>
#include <stdint.h>

#define D_EMBED 1024
#define D_HID   4096
#define N_TOK   4096
#define N_EXP   8
#define CAP     4096
#define NROWA   8448

typedef __attribute__((ext_vector_type(4))) float f32x4;
typedef __attribute__((ext_vector_type(8))) short bf16x8;

__device__ __forceinline__ unsigned short f2bf(float f) {
    unsigned int u = __builtin_bit_cast(unsigned int, f);
    u += 0x7fffu + ((u >> 16) & 1u);
    return (unsigned short)(u >> 16);
}
__device__ __forceinline__ float bf2f(unsigned short h) {
    unsigned int u = ((unsigned int)h) << 16;
    return __builtin_bit_cast(float, u);
}
__device__ __forceinline__ void gload_lds16(const void* g, void* l) {
    __builtin_amdgcn_global_load_lds(
        (const __attribute__((address_space(1))) unsigned int*)g,
        (__attribute__((address_space(3))) unsigned int*)l, 16, 0, 0);
}

// ------- merged: weight pack (blocks <49152) + gating (blocks >=49152) -------
__global__ __launch_bounds__(256) void pack_gate(const float* __restrict__ W1,
                                                 const float* __restrict__ W3,
                                                 const float* __restrict__ W2,
                                                 const float* __restrict__ x,
                                                 const float* __restrict__ Wg,
                                                 unsigned short* __restrict__ wt13,
                                                 unsigned short* __restrict__ wt2,
                                                 int* __restrict__ counts,
                                                 int* __restrict__ toks,
                                                 float* __restrict__ wgts,
                                                 int* __restrict__ slots) {
    int b = blockIdx.x;
    if (b < 32768) {
        int idx = b * 256 + threadIdx.x;
        int pc = idx & 8191, s = (idx >> 13) & 127, e = idx >> 20;
        int g = pc >> 4;
        int rc = ((g >> 1) << 4) + (pc & 15);
        const float* src = (g & 1 ? W3 : W1) + (size_t)e * (D_EMBED * D_HID)
                         + (size_t)(s * 8) * D_HID + rc;
        bf16x8 o;
#pragma unroll
        for (int j = 0; j < 8; ++j) o[j] = (short)f2bf(src[(size_t)j * D_HID]);
        *reinterpret_cast<bf16x8*>(wt13 + (size_t)e * (D_EMBED * 2 * D_HID)
                                   + ((size_t)s * (2 * D_HID) + pc) * 8) = o;
    } else if (b < 49152) {
        int idx = (b - 32768) * 256 + threadIdx.x;
        int col = idx & 1023, s = (idx >> 10) & 511, e = idx >> 19;
        const float* src = W2 + (size_t)e * (D_HID * D_EMBED) + (size_t)(s * 8) * D_EMBED + col;
        bf16x8 o;
#pragma unroll
        for (int j = 0; j < 8; ++j) o[j] = (short)f2bf(src[(size_t)j * D_EMBED]);
        *reinterpret_cast<bf16x8*>(wt2 + (size_t)e * (D_HID * D_EMBED)
                                   + ((size_t)s * D_EMBED + col) * 8) = o;
    } else {
        int gb = b - 49152;
        int wave = threadIdx.x >> 6;
        int lane = threadIdx.x & 63;
        int tok = gb * 4 + wave;
        const float* xp = x + (size_t)tok * D_EMBED;
        float acc[8] = {0, 0, 0, 0, 0, 0, 0, 0};
#pragma unroll
        for (int i = 0; i < 16; ++i) {
            int d = lane + 64 * i;
            float xv = xp[d];
            f32x4 w0 = *reinterpret_cast<const f32x4*>(Wg + (size_t)d * 8);
            f32x4 w1 = *reinterpret_cast<const f32x4*>(Wg + (size_t)d * 8 + 4);
            acc[0] += xv * w0[0]; acc[1] += xv * w0[1]; acc[2] += xv * w0[2]; acc[3] += xv * w0[3];
            acc[4] += xv * w1[0]; acc[5] += xv * w1[1]; acc[6] += xv * w1[2]; acc[7] += xv * w1[3];
        }
#pragma unroll
        for (int e = 0; e < 8; ++e)
            for (int s = 32; s; s >>= 1) acc[e] += __shfl_xor(acc[e], s, 64);
        if (lane == 0) {
            int i0 = 0; float v0 = acc[0];
#pragma unroll
            for (int e = 1; e < 8; ++e) if (acc[e] > v0) { v0 = acc[e]; i0 = e; }
            int i1 = -1; float v1 = -1e30f;
#pragma unroll
            for (int e = 0; e < 8; ++e) if (e != i0 && acc[e] > v1) { v1 = acc[e]; i1 = e; }
            float ex = __expf(v1 - v0);
            float w0 = 1.0f / (1.0f + ex);
            float w1 = 1.0f - w0;
            int p0 = atomicAdd(&counts[i0], 1);
            toks[i0 * CAP + p0] = tok; wgts[i0 * CAP + p0] = w0; slots[i0 * CAP + p0] = 0;
            int p1 = atomicAdd(&counts[i1], 1);
            toks[i1 * CAP + p1] = tok; wgts[i1 * CAP + p1] = w1; slots[i1 * CAP + p1] = 1;
        }
    }
}

// ------- gather x rows into compacted k-packed A (tok2row folded in) -------
__global__ __launch_bounds__(256) void gather_x_kernel(
    const float* __restrict__ x, const int* __restrict__ counts,
    const int* __restrict__ toks, const int* __restrict__ slots,
    int* __restrict__ tok2row, unsigned short* __restrict__ xg) {
    int rt = blockIdx.x;
    int e = -1, tb = 0, osum = 0, rowbase = 0, cnt = 0, off = 0;
    for (int ee = 0; ee < N_EXP; ++ee) {
        int c = counts[ee];
        int nt = (c + 63) >> 6;
        if (rt < tb + nt) { e = ee; rowbase = (rt - tb) << 6; cnt = c; off = osum; break; }
        tb += nt; osum += c;
    }
    if (e < 0) return;
    int kb = blockIdx.y;
    int t = threadIdx.x;
    if (kb == 0 && t < 64) {
        int pos = rowbase + t;
        if (pos < cnt) {
            int i = e * CAP + pos;
            tok2row[toks[i] * 2 + slots[i]] = off + pos;
        }
    }
    __shared__ unsigned short lds[64][72];
    int r = t >> 2, ck = t & 3;
    int pos = rowbase + r;
    unsigned short tmp[16];
    if (pos < cnt) {
        int tok = toks[e * CAP + pos];
        const float* src = x + (size_t)tok * D_EMBED + kb * 64 + ck * 16;
#pragma unroll
        for (int i = 0; i < 4; ++i) {
            f32x4 v = *reinterpret_cast<const f32x4*>(src + i * 4);
#pragma unroll
            for (int j = 0; j < 4; ++j) tmp[i * 4 + j] = f2bf(v[j]);
        }
    } else {
#pragma unroll
        for (int i = 0; i < 16; ++i) tmp[i] = 0;
    }
#pragma unroll
    for (int i = 0; i < 16; ++i) lds[r][ck * 16 + i] = tmp[i];
    __syncthreads();
    int sl = t >> 5, rr = (t & 31) * 2;
#pragma unroll
    for (int w = 0; w < 2; ++w) {
        int rw = rr + w;
        if (rowbase + rw >= cnt) continue;
        bf16x8 o;
#pragma unroll
        for (int j = 0; j < 8; ++j) o[j] = (short)lds[rw][sl * 8 + j];
        *reinterpret_cast<bf16x8*>(xg + ((size_t)(kb * 8 + sl) * NROWA + off + rowbase + rw) * 8) = o;
    }
}

// ======= GEMM1: 128x128p, 4 waves (2Mx2N), ring-2 half-K(32), vmcnt(4), 4-5 blocks/CU =======
// grid (x = packed coltile 64, y = rowtile 72): XCD = x%8 -> B panel pinned per XCD
__global__ __launch_bounds__(256, 4) void gemm1_kernel(
    const unsigned short* __restrict__ xg,
    const unsigned short* __restrict__ wt13,
    const int* __restrict__ counts,
    const float* __restrict__ wgts,
    unsigned short* __restrict__ hp) {
    int rt = blockIdx.y;
    int e = -1, tb = 0, osum = 0, rowbase = 0, cnt = 0, off = 0;
#pragma unroll 1
    for (int ee = 0; ee < N_EXP; ++ee) {
        int c = counts[ee];
        int nt = (c + 127) >> 7;
        if (rt < tb + nt) { e = ee; rowbase = (rt - tb) << 7; cnt = c; off = osum; break; }
        tb += nt; osum += c;
    }
    if (e < 0) return;

    __shared__ __align__(16) char lds[2][16384];   // slot: A 8K [sl4][row128] | B 8K [sl4][pc128]

    int t = threadIdx.x, lane = t & 63, w = t >> 6;   // 4 waves, 2Mx2N
    int wr = w >> 1, wc = w & 1;
    int q = lane >> 4, p = lane & 15;

    const size_t ASTEP = (size_t)4 * NROWA * 16;
    const size_t BSTEP = (size_t)4 * (2 * D_HID) * 16;
    const size_t A2 = (size_t)2 * NROWA * 16;          // i=1 extra offset
    const size_t B2 = (size_t)2 * (2 * D_HID) * 16;
    const char* aS = (const char*)xg + ((size_t)(t >> 7) * NROWA + off + rowbase + (t & 127)) * 16;
    const char* bS = (const char*)wt13 + (size_t)e * D_EMBED * 2 * D_HID * 2
                   + ((size_t)(t >> 7) * (2 * D_HID) + blockIdx.x * 128 + (t & 127)) * 16;

    int wslot = 0;
    auto STG = [&]() {                                 // 4 gloads/thread
        char* L = &lds[wslot][0];
        wslot ^= 1;
        gload_lds16(aS, L + t * 16);
        gload_lds16(aS + A2, L + 4096 + t * 16);
        gload_lds16(bS, L + 8192 + t * 16);
        gload_lds16(bS + B2, L + 12288 + t * 16);
        aS += ASTEP; bS += BSTEP;
    };

    f32x4 acc[4][4] = {};

    STG();
#pragma unroll 1
    for (int h = 0; h < 32; ++h) {                 // K=1024, half-K=32
        if (h < 31) STG();
        if (h < 31) asm volatile("s_waitcnt vmcnt(4)" ::: "memory");
        else        asm volatile("s_waitcnt vmcnt(0)" ::: "memory");
        __builtin_amdgcn_s_barrier();
        __builtin_amdgcn_sched_barrier(0);
        const char* L = &lds[h & 1][0];
        bf16x8 af[4], bf[4];
#pragma unroll
        for (int m = 0; m < 4; ++m)
            af[m] = *reinterpret_cast<const bf16x8*>(L + (q * 128 + wr * 64 + m * 16 + p) * 16);
#pragma unroll
        for (int n = 0; n < 4; ++n)
            bf[n] = *reinterpret_cast<const bf16x8*>(L + 8192 + (q * 128 + wc * 64 + n * 16 + p) * 16);
        __builtin_amdgcn_s_setprio(1);
#pragma unroll
        for (int n = 0; n < 4; ++n)
#pragma unroll
            for (int m = 0; m < 4; ++m)
                acc[m][n] = __builtin_amdgcn_mfma_f32_16x16x32_bf16(af[m], bf[n], acc[m][n], 0, 0, 0);
        __builtin_amdgcn_s_setprio(0);
    }

    // epilogue: (even n = W1, odd n = W3) -> SwiGLU * gate-weight -> hp (k-packed)
#pragma unroll
    for (int m = 0; m < 4; ++m) {
#pragma unroll
        for (int reg = 0; reg < 4; ++reg) {
            int rl = wr * 64 + m * 16 + q * 4 + reg;
            int grow = rowbase + rl;
            if (grow >= cnt) continue;
            float wgt = wgts[e * CAP + grow];
            size_t row = (size_t)(off + grow);
#pragma unroll
            for (int np = 0; np < 2; ++np) {
                float a1 = acc[m][2 * np][reg];
                float a3 = acc[m][2 * np + 1][reg];
                float hv = (a1 / (1.0f + __expf(-a1))) * a3 * wgt;
                int rc = (blockIdx.x * 4 + wc * 2 + np) * 16 + p;
                hp[((size_t)(rc >> 3) * NROWA + row) * 8 + (rc & 7)] = f2bf(hv);
            }
        }
    }
}

// ======= GEMM2: 128x128, 4 waves, split-K=4, ring-2 vmcnt(4) =======
// grid (x = coltile 8, y = rowtile 72, z = split 4): XCD = x -> B col panel pinned
__global__ __launch_bounds__(256, 4) void gemm2_kernel(
    const unsigned short* __restrict__ hp,
    const unsigned short* __restrict__ wt2,
    const int* __restrict__ counts,
    unsigned short* __restrict__ pbuf) {
    int rt = blockIdx.y;
    int e = -1, tb = 0, osum = 0, rowbase = 0, cnt = 0, off = 0;
#pragma unroll 1
    for (int ee = 0; ee < N_EXP; ++ee) {
        int c = counts[ee];
        int nt = (c + 127) >> 7;
        if (rt < tb + nt) { e = ee; rowbase = (rt - tb) << 7; cnt = c; off = osum; break; }
        tb += nt; osum += c;
    }
    if (e < 0) return;
    int s2 = blockIdx.z;

    __shared__ __align__(16) char lds[2][16384];

    int t = threadIdx.x, lane = t & 63, w = t >> 6;
    int wr = w >> 1, wc = w & 1;
    int q = lane >> 4, p = lane & 15;

    const size_t ASTEP = (size_t)4 * NROWA * 16;
    const size_t BSTEP = (size_t)4 * D_EMBED * 16;
    const size_t A2 = (size_t)2 * NROWA * 16;
    const size_t B2 = (size_t)2 * D_EMBED * 16;
    const char* aS = (const char*)hp
        + ((size_t)(s2 * 128 + (t >> 7)) * NROWA + off + rowbase + (t & 127)) * 16;
    const char* bS = (const char*)wt2 + (size_t)e * D_HID * D_EMBED * 2
        + ((size_t)(s2 * 128 + (t >> 7)) * D_EMBED + blockIdx.x * 128 + (t & 127)) * 16;

    int wslot = 0;
    auto STG = [&]() {
        char* L = &lds[wslot][0];
        wslot ^= 1;
        gload_lds16(aS, L + t * 16);
        gload_lds16(aS + A2, L + 4096 + t * 16);
        gload_lds16(bS, L + 8192 + t * 16);
        gload_lds16(bS + B2, L + 12288 + t * 16);
        aS += ASTEP; bS += BSTEP;
    };

    f32x4 acc[4][4] = {};

    STG();
#pragma unroll 1
    for (int h = 0; h < 32; ++h) {                 // 1024 k per split, half-K=32
        if (h < 31) STG();
        if (h < 31) asm volatile("s_waitcnt vmcnt(4)" ::: "memory");
        else        asm volatile("s_waitcnt vmcnt(0)" ::: "memory");
        __builtin_amdgcn_s_barrier();
        __builtin_amdgcn_sched_barrier(0);
        const char* L = &lds[h & 1][0];
        bf16x8 af[4], bf[4];
#pragma unroll
        for (int m = 0; m < 4; ++m)
            af[m] = *reinterpret_cast<const bf16x8*>(L + (q * 128 + wr * 64 + m * 16 + p) * 16);
#pragma unroll
        for (int n = 0; n < 4; ++n)
            bf[n] = *reinterpret_cast<const bf16x8*>(L + 8192 + (q * 128 + wc * 64 + n * 16 + p) * 16);
        __builtin_amdgcn_s_setprio(1);
#pragma unroll
        for (int n = 0; n < 4; ++n)
#pragma unroll
            for (int m = 0; m < 4; ++m)
                acc[m][n] = __builtin_amdgcn_mfma_f32_16x16x32_bf16(af[m], bf[n], acc[m][n], 0, 0, 0);
        __builtin_amdgcn_s_setprio(0);
    }

    unsigned short* pb = pbuf + (size_t)s2 * 8192 * D_EMBED;
#pragma unroll
    for (int m = 0; m < 4; ++m)
#pragma unroll
        for (int reg = 0; reg < 4; ++reg) {
            int rl = wr * 64 + m * 16 + q * 4 + reg;
            int grow = rowbase + rl;
            if (grow >= cnt) continue;
            unsigned short* dst = pb + (size_t)(off + grow) * D_EMBED + blockIdx.x * 128 + wc * 64;
#pragma unroll
            for (int n = 0; n < 4; ++n) dst[n * 16 + p] = f2bf(acc[m][n][reg]);
        }
}

// ---------------- combine: out[tok] = sum over 2 rows x 4 k-splits (bf16 pbuf) ----------------
__global__ __launch_bounds__(256) void combine_kernel(const unsigned short* __restrict__ pbuf,
                                                      const int* __restrict__ tok2row,
                                                      float* __restrict__ out) {
    int i = blockIdx.x * 256 + threadIdx.x;        // N_TOK * 128, 8 cols each
    int tok = i >> 7, c0 = (i & 127) * 8;
    int r0 = tok2row[tok * 2], r1 = tok2row[tok * 2 + 1];
    const size_t SP = (size_t)8192 * D_EMBED;
    float s[8] = {0, 0, 0, 0, 0, 0, 0, 0};
#pragma unroll
    for (int sp = 0; sp < 4; ++sp) {
        bf16x8 a = *reinterpret_cast<const bf16x8*>(pbuf + sp * SP + (size_t)r0 * D_EMBED + c0);
        bf16x8 b = *reinterpret_cast<const bf16x8*>(pbuf + sp * SP + (size_t)r1 * D_EMBED + c0);
#pragma unroll
        for (int j = 0; j < 8; ++j)
            s[j] += bf2f((unsigned short)a[j]) + bf2f((unsigned short)b[j]);
    }
    float* op = out + (size_t)tok * D_EMBED + c0;
    f32x4 lo = {s[0], s[1], s[2], s[3]}, hi = {s[4], s[5], s[6], s[7]};
    *reinterpret_cast<f32x4*>(op) = lo;
    *reinterpret_cast<f32x4*>(op + 4) = hi;
}

extern "C" void kernel_launch(void* const* d_in, const int* in_sizes, int n_in,
                              void* d_out, int out_size, void* d_ws, size_t ws_size,
                              hipStream_t stream) {
    const float* x  = (const float*)d_in[0];
    const float* Wg = (const float*)d_in[1];
    const float* W1 = (const float*)d_in[2];
    const float* W3 = (const float*)d_in[3];
    const float* W2 = (const float*)d_in[4];
    float* out = (float*)d_out;

    char* ws = (char*)d_ws;
    size_t szW = (size_t)N_EXP * D_EMBED * D_HID;
    unsigned short* wt13 = (unsigned short*)ws; ws += szW * 2 * 2;     // 128 MB
    unsigned short* wt2  = (unsigned short*)ws; ws += szW * 2;         // 64 MB
    unsigned short* hp   = (unsigned short*)ws; ws += (size_t)(D_HID / 8) * NROWA * 8 * 2;
    unsigned short* xg   = (unsigned short*)ws; ws += (size_t)(D_EMBED / 8) * NROWA * 8 * 2;
    int*   toks    = (int*)ws;   ws += (size_t)N_EXP * CAP * 4;
    float* wgts    = (float*)ws; ws += (size_t)N_EXP * CAP * 4;
    int*   slots   = (int*)ws;   ws += (size_t)N_EXP * CAP * 4;
    int*   tok2row = (int*)ws;   ws += (size_t)N_TOK * 2 * 4;
    int*   counts  = (int*)ws;   ws += 8 * 4;
    // pbuf bf16 (64 MB: 4 splits x 8192 x 1024) aliases wt13 (dead after gemm1)
    unsigned short* pbuf = (unsigned short*)wt13;

    hipMemsetAsync(counts, 0, 8 * sizeof(int), stream);

    pack_gate<<<49152 + N_TOK / 4, 256, 0, stream>>>(W1, W3, W2, x, Wg, wt13, wt2,
                                                     counts, toks, wgts, slots);
    gather_x_kernel<<<dim3(136, D_EMBED / 64), 256, 0, stream>>>(x, counts, toks, slots, tok2row, xg);
    gemm1_kernel<<<dim3(64, 72), 256, 0, stream>>>(xg, wt13, counts, wgts, hp);
    gemm2_kernel<<<dim3(8, 72, 4), 256, 0, stream>>>(hp, wt2, counts, pbuf);
    combine_kernel<<<(N_TOK * 128) / 256, 256, 0, stream>>>(pbuf, tok2row, out);
}